// Round 7
// baseline (11333.781 us; speedup 1.0000x reference)
//
#include <hip/hip_runtime.h>

#define Tt 256
#define NWG 32
#define NT 512
#define ETAf 1e-3f
#define SPIN_CAP (1 << 25)

typedef float f4 __attribute__((ext_vector_type(4)));

// ---------------- ws layout (byte offsets) ----------------
// flags:  unsigned[32*32*16]   @ 0        (64 KB)  zeroed each call
// exch:   float[2][32][160]    @ 65536    (40 KB)
// S0sh:   float[256*128]       @ 131072   (128 KB)
// SBsh:   float[256*128]       @ 262144   (128 KB)
// whist:  float[256*256]       @ 393216   (256 KB)
// uhist:  float[256*128]       @ 655360   (128 KB)  end 786432

__device__ __forceinline__ unsigned ldflag(const unsigned* p) {
  return __hip_atomic_load(p, __ATOMIC_RELAXED, __HIP_MEMORY_SCOPE_AGENT);
}
__device__ __forceinline__ void stflag(unsigned* p, unsigned v) {
  __hip_atomic_store(p, v, __ATOMIC_RELAXED, __HIP_MEMORY_SCOPE_AGENT);
}
__device__ __forceinline__ f4 ld4_issue(const float* p) {
  f4 r;
  asm volatile("global_load_dwordx4 %0, %1, off sc0 sc1" : "=v"(r) : "v"(p) : "memory");
  return r;
}
__device__ __forceinline__ void st4_bypass(float* p, f4 v) {
  asm volatile("global_store_dwordx4 %0, %1, off sc0 sc1" :: "v"(p), "v"(v) : "memory");
}
__device__ __forceinline__ void st1_bypass(float* p, float v) {
  asm volatile("global_store_dword %0, %1, off sc0 sc1" :: "v"(p), "v"(v) : "memory");
}
__device__ __forceinline__ void waitvm() { asm volatile("s_waitcnt vmcnt(0)" ::: "memory"); }
__device__ __forceinline__ float wred64(float p) {
  p += __shfl_xor(p, 1); p += __shfl_xor(p, 2); p += __shfl_xor(p, 4);
  p += __shfl_xor(p, 8); p += __shfl_xor(p, 16); p += __shfl_xor(p, 32);
  return p;
}

__global__ void init_ws_kernel(unsigned* w) {
  const int i = blockIdx.x * 256 + threadIdx.x;
  if (i < 32 * 32 * 16) w[i] = 0u;
}

__global__ __launch_bounds__(NT, 1)
void osf_main(const float* __restrict__ Am, const float* __restrict__ Bm,
              const float* __restrict__ Qmat, const float* __restrict__ Rm,
              const float* __restrict__ Km, const float* __restrict__ phi,
              const float* __restrict__ sigma, const float* __restrict__ phis,
              const float* __restrict__ M0, const float* __restrict__ Ms,
              const float* __restrict__ x0, const float* __restrict__ W0,
              float* __restrict__ out, char* __restrict__ ws) {
  unsigned* flags = (unsigned*)ws;
  float* exch = (float*)(ws + 65536);
  float* S0sh = (float*)(ws + 131072);
  float* SBsh = (float*)(ws + 262144);
  float* whist = (float*)(ws + 393216);
  float* uhist = (float*)(ws + 655360);

  const int r = blockIdx.x, tid = threadIdx.x;
  const int n = tid >> 2, dsub = tid & 3;   // M layout: M[r][n][dsub*64+e]
  const int d0 = r * 8;                     // owned d rows (A/xold slices)
  const float s4h = sqrtf(sqrtf(sigma[r]));

  __shared__ float s_gbuf[32][160];   // gathered exchange
  __shared__ float s_P[20][128];      // P'' partial (slack)
  __shared__ float s_A[8][256];       // A own rows
  __shared__ float s_K[4][256];       // K own rows
  __shared__ float s_S1[8][128];      // S1 own rows (phis row1 fold of Ms)
  __shared__ float s_vb[2][4][65];    // v double-buffer, padded
  __shared__ float s_prev[256], s_x[256], s_w[256], s_xn[256], s_lx[256], s_W0[256];
  __shared__ float s_u[128], s_g[128], s_lu[128];
  __shared__ float s_pub[160];
  __shared__ float s_fold[8], s_red[8];

  // ---------------- init ----------------
  for (int i = tid; i < 2048; i += NT) ((float*)s_A)[i] = Am[(size_t)d0 * 256 + i];
  for (int i = tid; i < 1024; i += NT) ((float*)s_K)[i] = Km[(size_t)(4 * r) * 256 + i];
  for (int i = tid; i < 256; i += NT) {
    s_W0[i] = W0[(size_t)i * 512];
    s_x[i] = x0[i];
    s_w[i] = 0.f; s_prev[i] = 0.f; s_xn[i] = 0.f;
  }
  for (int i = tid; i < 260; i += NT) { ((float*)s_vb[0])[i] = 0.f; ((float*)s_vb[1])[i] = 0.f; }
  for (int i = tid; i < 160; i += NT) s_pub[i] = 0.f;
  if (tid < 128) { s_u[tid] = 0.f; s_g[tid] = 0.f; }
  for (int i = tid; i < 1024; i += NT) {   // S1 own + shared S0/SB write
    const int row = i >> 7, nn = i & 127;
    float a1 = 0.f, a0 = 0.f;
    for (int k = 0; k < 20; ++k) {
      const float m = Ms[((size_t)k * 256 + d0 + row) * 128 + nn];
      a0 = fmaf(phis[k], m, a0);
      a1 = fmaf(phis[20 + k], m, a1);
    }
    s_S1[row][nn] = a1;
    st1_bypass(S0sh + (size_t)(d0 + row) * 128 + nn, a0);
    st1_bypass(SBsh + (size_t)(d0 + row) * 128 + nn, a0 - Bm[(size_t)(d0 + row) * 128 + nn]);
  }
  float Mreg[64];
  {
    const float* mp = M0 + ((size_t)r * 128 + n) * 256 + dsub * 64;
#pragma unroll
    for (int e = 0; e < 64; ++e) Mreg[e] = mp[e];
  }
  __syncthreads();
  if (tid < 256) s_vb[0][tid >> 6][tid & 63] = s_W0[tid] * phi[r];  // v_0
  waitvm();
  __syncthreads();
  if (tid < 64) {
    waitvm();
    if (tid < 32) stflag(&flags[(r * 32 + tid) * 16], 1u);
  }
  if (tid < 32) {  // init poll (S0/SB visibility)
    const unsigned* fp = &flags[(tid * 32 + r) * 16];
    int guard = 0;
    while (ldflag(fp) < 1u && ++guard < SPIN_CAP) {}
  }
  __syncthreads();

  // ---------------- main loop: ONE exchange per step ----------------
  for (int t = 0; t < Tt; ++t) {
    const unsigned want = (unsigned)(t + 2);
    const int par = t & 1;

    // ===== publish(t): cnp (M-update fused) + Ax + Kx; xold slot pre-filled =====
    {
      float coef = 0.f;
      if (t > 0) coef = ETAf * s4h * s_g[n];
      const float* vc = &s_vb[par][dsub][0];
      const float* vpv = &s_vb[par ^ 1][dsub][0];
      float acc = 0.f;
#pragma unroll
      for (int e = 0; e < 64; ++e) {
        Mreg[e] = fmaf(-coef, vpv[e], Mreg[e]);
        acc = fmaf(Mreg[e], vc[e], acc);
      }
      acc += __shfl_xor(acc, 1); acc += __shfl_xor(acc, 2);
      if (dsub == 0) s_pub[n] = s4h * acc;
    }
    {  // Axsl = A[own 8]·x_t
      const int row = tid >> 6, j = tid & 63;
      float a = s_A[row][j] * s_x[j] + s_A[row][j + 64] * s_x[j + 64] +
                s_A[row][j + 128] * s_x[j + 128] + s_A[row][j + 192] * s_x[j + 192];
      a = wred64(a);
      if (j == 0) s_pub[128 + row] = a;
    }
    if (tid < 256) {  // Kxsl = K[own 4]·x_t
      const int row = tid >> 6, j = tid & 63;
      float a = s_K[row][j] * s_x[j] + s_K[row][j + 64] * s_x[j + 64] +
                s_K[row][j + 128] * s_x[j + 128] + s_K[row][j + 192] * s_x[j + 192];
      a = wred64(a);
      if (j == 0) s_pub[136 + row] = a;
    }
    __syncthreads();
    if (tid < 64) {
      if (tid < 40)
        st4_bypass(exch + ((size_t)par * 32 + r) * 160 + tid * 4, *(const f4*)&s_pub[tid * 4]);
      waitvm();
      if (tid < 32) stflag(&flags[(r * 32 + tid) * 16], want);
    }

    // ===== slack(t): convolutions from flag-safe history + local newest terms =====
    if (tid < 256) {  // pre_v for v_{t+1}: W0 + w_{t-1}(local) + whist(<=t-2)
      const int d = tid;
      float a = s_W0[d] * phi[(size_t)(t + 1) * 32 + r];
      if (t >= 1) a = fmaf(s_w[d], phi[32 + r], a);
      for (int s2 = 0; s2 <= t - 2; ++s2)
        a = fmaf(whist[(size_t)s2 * 256 + d], phi[(size_t)(t - s2) * 32 + r], a);
      s_prev[d] = a;
    }
    {  // P'' (s<=t-1) for xoldsl(t+2): u_{t-1}(local, phis row2) + uhist(<=t-2)
      const int n2 = tid & 127, kg = tid >> 7;
      float p5[5] = {0.f, 0.f, 0.f, 0.f, 0.f};
      if (t >= 1) {
        const float ul = s_u[n2];
#pragma unroll
        for (int j = 0; j < 5; ++j) p5[j] = fmaf(ul, phis[40 + kg * 5 + j], p5[j]);
      }
      for (int s2 = 0; s2 <= t - 2; ++s2) {
        const float us = uhist[(size_t)s2 * 128 + n2];
        const int row = (t + 1 - s2) * 20 + kg * 5;
#pragma unroll
        for (int j = 0; j < 5; ++j) p5[j] = fmaf(us, phis[row + j], p5[j]);
      }
#pragma unroll
      for (int j = 0; j < 5; ++j) s_P[kg * 5 + j][n2] = p5[j];
    }
    if (t >= 1 && ((t - 1) & 31) == r) {  // deferred loss(t-1) from stash (WG-uniform)
      const int d = tid >> 1, half = tid & 1;
      const float* qr = Qmat + (size_t)d * 256 + half * 128;
      float qa = 0.f;
#pragma unroll 16
      for (int j = 0; j < 128; ++j) qa = fmaf(qr[j], s_lx[half * 128 + j], qa);
      qa += __shfl_xor(qa, 1);
      float tot = (half == 0) ? qa * s_lx[d] : 0.f;
      {
        const float* rr2 = Rm + (size_t)(tid >> 2) * 128 + (tid & 3) * 32;
        float ra = 0.f;
#pragma unroll
        for (int j = 0; j < 32; ++j) ra = fmaf(rr2[j], s_lu[(tid & 3) * 32 + j], ra);
        ra += __shfl_xor(ra, 1); ra += __shfl_xor(ra, 2);
        if ((tid & 3) == 0) tot += ra * s_lu[tid >> 2];
      }
      tot = wred64(tot);
      if ((tid & 63) == 0) s_red[tid >> 6] = tot;
      __syncthreads();
      if (tid == 0) {
        float ss = 0.f;
        for (int i3 = 0; i3 < 8; ++i3) ss += s_red[i3];
        out[t - 1] = ss;
      }
    }
    __syncthreads();
    {  // foldpre = Ms(own) : P''
      const int row = tid >> 6, i = tid & 63;
      float f = 0.f;
      for (int m2 = i; m2 < 2560; m2 += 64) {
        const int k = m2 >> 7, nn = m2 & 127;
        f = fmaf(Ms[((size_t)k * 256 + d0 + row) * 128 + nn], s_P[k][nn], f);
      }
      f = wred64(f);
      if (i == 0) s_fold[row] = f;
    }

    // ===== poll(t): 1 poller per replica-flag line =====
    if (tid < 32) {
      const unsigned* fp = &flags[(tid * 32 + r) * 16];
      int guard = 0;
      while (ldflag(fp) < want && ++guard < SPIN_CAP) {}
    }
    __syncthreads();

    // ===== gather: 1280 dwordx4, staggered by producer =====
    {
      const int i0 = tid, i1 = tid + 512, i2 = tid + 1024;
      const int p0 = i0 / 40, c0 = i0 - p0 * 40;
      const int p1 = i1 / 40, c1 = i1 - p1 * 40;
      const int pp0 = (p0 + r) & 31, pp1 = (p1 + r) & 31;
      f4 a0 = ld4_issue(exch + ((size_t)par * 32 + pp0) * 160 + c0 * 4);
      f4 a1 = ld4_issue(exch + ((size_t)par * 32 + pp1) * 160 + c1 * 4);
      f4 a2;
      int pp2 = 0, c2 = 0;
      if (i2 < 1280) {
        const int p2 = i2 / 40; c2 = i2 - p2 * 40; pp2 = (p2 + r) & 31;
        a2 = ld4_issue(exch + ((size_t)par * 32 + pp2) * 160 + c2 * 4);
      }
      waitvm();
      *(f4*)&s_gbuf[pp0][c0 * 4] = a0;
      *(f4*)&s_gbuf[pp1][c1 * 4] = a1;
      if (i2 < 1280) *(f4*)&s_gbuf[pp2][c2 * 4] = a2;
    }
    __syncthreads();

    // ===== post(t): u_t, g_t, w_t, x_{t+1}, v_{t+1} — all local =====
    if (tid < 128) {
      float s = 0.f;
#pragma unroll 8
      for (int p = 0; p < 32; ++p) s += s_gbuf[p][tid];
      s -= s_gbuf[tid >> 2][136 + (tid & 3)];   // -Kx
      s_u[tid] = s;
      if (r == 0) st1_bypass(uhist + (size_t)t * 128 + tid, s);
    }
    __syncthreads();
    if ((t & 31) == r && tid < 256) {  // stash x_t,u_t for deferred loss
      s_lx[tid] = s_x[tid];
      if (tid < 128) s_lu[tid] = s_u[tid];
    }
    {  // g_t = 2 R u_t
      float a = 0.f;
      const float* rr = Rm + (size_t)n * 128 + dsub * 32;
#pragma unroll
      for (int j = 0; j < 32; ++j) a = fmaf(rr[j], s_u[dsub * 32 + j], a);
      a += __shfl_xor(a, 1); a += __shfl_xor(a, 2);
      if (dsub == 0) s_g[n] = 2.f * a;
    }
    {  // SB·u, S0·u -> w_t, x_{t+1}
      const int d = tid >> 1, half = tid & 1;
      const float* sbr = SBsh + (size_t)d * 128 + half * 64;
      const float* s0r = S0sh + (size_t)d * 128 + half * 64;
      const float* ur = s_u + half * 64;
      float asb = 0.f, as0 = 0.f;
#pragma unroll
      for (int j = 0; j < 64; ++j) {
        asb = fmaf(sbr[j], ur[j], asb);
        as0 = fmaf(s0r[j], ur[j], as0);
      }
      asb += __shfl_xor(asb, 1); as0 += __shfl_xor(as0, 1);
      if (half == 0) {
        const float xo = s_gbuf[d >> 3][140 + (d & 7)];
        const float ax = s_gbuf[d >> 3][128 + (d & 7)];
        const float wv = xo + asb - ax;          // w_t
        s_w[d] = wv;
        s_xn[d] = xo + as0;                      // x_{t+1}
        if (r == 0) st1_bypass(whist + (size_t)t * 256 + d, wv);
      }
    }
    __syncthreads();
    if (tid < 256) {
      s_x[tid] = s_xn[tid];
      s_vb[par ^ 1][tid >> 6][tid & 63] = fmaf(s_w[tid], phi[r], s_prev[tid]);  // v_{t+1}
    }
    {  // xoldsl(t+2) = foldpre + S1(own)·u_t  -> next publish
      const int row = tid >> 6, j = tid & 63;
      float a = s_S1[row][j] * s_u[j] + s_S1[row][j + 64] * s_u[j + 64];
      a = wred64(a);
      if (j == 0) s_pub[140 + row] = s_fold[row] + a;
    }
    waitvm();
    __syncthreads();
  }

  // ---------------- final deferred loss (t = 255) ----------------
  if (((Tt - 1) & 31) == r) {
    const int d = tid >> 1, half = tid & 1;
    const float* qr = Qmat + (size_t)d * 256 + half * 128;
    float qa = 0.f;
#pragma unroll 16
    for (int j = 0; j < 128; ++j) qa = fmaf(qr[j], s_lx[half * 128 + j], qa);
    qa += __shfl_xor(qa, 1);
    float tot = (half == 0) ? qa * s_lx[d] : 0.f;
    {
      const float* rr2 = Rm + (size_t)(tid >> 2) * 128 + (tid & 3) * 32;
      float ra = 0.f;
#pragma unroll
      for (int j = 0; j < 32; ++j) ra = fmaf(rr2[j], s_lu[(tid & 3) * 32 + j], ra);
      ra += __shfl_xor(ra, 1); ra += __shfl_xor(ra, 2);
      if ((tid & 3) == 0) tot += ra * s_lu[tid >> 2];
    }
    tot = wred64(tot);
    if ((tid & 63) == 0) s_red[tid >> 6] = tot;
    __syncthreads();
    if (tid == 0) {
      float ss = 0.f;
      for (int i3 = 0; i3 < 8; ++i3) ss += s_red[i3];
      out[Tt - 1] = ss;
    }
  }
}

extern "C" void kernel_launch(void* const* d_in, const int* in_sizes, int n_in,
                              void* d_out, int out_size, void* d_ws, size_t ws_size,
                              hipStream_t stream) {
  (void)in_sizes; (void)n_in; (void)out_size; (void)ws_size;
  const float* A   = (const float*)d_in[0];
  const float* B   = (const float*)d_in[1];
  const float* Qm  = (const float*)d_in[2];
  const float* R   = (const float*)d_in[3];
  const float* K   = (const float*)d_in[4];
  const float* phi = (const float*)d_in[5];
  const float* sig = (const float*)d_in[6];
  const float* phs = (const float*)d_in[7];
  const float* M0  = (const float*)d_in[8];
  const float* Ms  = (const float*)d_in[9];
  const float* x0  = (const float*)d_in[10];
  const float* W0  = (const float*)d_in[11];
  // d_in[12] = U0 (zeros, unused)

  // replica flags must be re-zeroed every call (monotone tags)
  init_ws_kernel<<<64, 256, 0, stream>>>((unsigned*)d_ws);
  osf_main<<<NWG, NT, 0, stream>>>(A, B, Qm, R, K, phi, sig, phs, M0, Ms, x0, W0,
                                   (float*)d_out, (char*)d_ws);
}